// Round 12
// baseline (492.751 us; speedup 1.0000x reference)
//
#include <hip/hip_runtime.h>
#include <cfloat>
#include <cmath>

#define NB_CODE 1024
#define CODE_DIM 64
#define NROWS (32 * 8192)          // N*T = 262144
#define NTC ((size_t)NROWS * CODE_DIM)
#define TAU 0.05f                  // proven in r11 for the f16 single-product error model
#define NBLK 512
#define ITERS (NROWS / 16 / NBLK)  // 32 row-tiles per block

typedef __attribute__((ext_vector_type(8))) _Float16 half8;
typedef __attribute__((ext_vector_type(4))) float f32x4;

// ws layout (32-bit words):
//   0..1023      counts (u32)
//   1024         loss_sum (f32 atomic)
//   1025         flag_count (u32)
//   1026..1027   pad
//   1028..2051   cnorm f32[1024]
//   2052..34819  cbp: fragment-major f16 of (-2*cb), 128 KB
//                entry e = ((T*2 + f)*64 + lane), 16B each (T = tile 0..63)
//   34820..      flaglist u32[] (row<<10 | oldj)
#define W_LOSS 1024
#define W_FLAGCNT 1025
#define W_CNORM 1028
#define W_CBP 2052
#define W_FLAGLIST 34820

// ---- prep: cnorm + fragment-major f16 of (-2*codebook) ----
// B-frag (16x16x32): lane = lg*16+li holds col=li, k = 32*f + 8*lg + i.
__global__ void prep_kernel(const float* __restrict__ cb, float* __restrict__ ws) {
    int j = blockIdx.x * blockDim.x + threadIdx.x;
    if (j >= NB_CODE) return;
    float* cnorm = ws + W_CNORM;
    half8* cbp = (half8*)(ws + W_CBP);
    const int t = j >> 4, li = j & 15;

    float c2v[CODE_DIM];
    const float4* c4 = reinterpret_cast<const float4*>(cb + (size_t)j * CODE_DIM);
    float s = 0.f;
#pragma unroll
    for (int q = 0; q < 16; ++q) {
        float4 v = c4[q];
        float e[4] = {v.x, v.y, v.z, v.w};
#pragma unroll
        for (int u = 0; u < 4; ++u) {
            s = fmaf(e[u], e[u], s);
            c2v[q * 4 + u] = -2.f * e[u];
        }
    }
    cnorm[j] = s;

#pragma unroll
    for (int f = 0; f < 2; ++f) {
#pragma unroll
        for (int lg = 0; lg < 4; ++lg) {
            half8 h8;
#pragma unroll
            for (int i = 0; i < 8; ++i)
                h8[i] = (_Float16)c2v[32 * f + 8 * lg + i];   // RNE
            cbp[(size_t)(t * 2 + f) * 64 + lg * 16 + li] = h8;
        }
    }
}

// ---- main: codebook-stationary-in-registers, LDS cross-wave argmin merge ----
// 1024 threads = 16 waves; wave w owns codes [w*64, w*64+64) in 8 half8 regs.
// Per iteration: one 16-row x-tile staged to LDS; zero global loads in the
// distance loop. Per-row argmin merged across the 16 waves through LDS.
__global__ __launch_bounds__(1024) void vq_cs_kernel(
    const float* __restrict__ x, const float* __restrict__ cb,
    float* __restrict__ ws, float* __restrict__ out, unsigned int flag_cap)
{
    __shared__ float sx[16][68];          // padded: stride 68 -> conflict-free ds_read
    __shared__ unsigned spb[16][16];      // [wave][row] best dist bits (f32, positive)
    __shared__ int      spj[16][16];      // [wave][row] best code
    __shared__ float    sps[16][16];      // [wave][row] second-best dist
    __shared__ int      sj[16];           // merged winner per row

    const int tid = threadIdx.x;
    const int w = tid >> 6, lane = tid & 63;
    const int lg = lane >> 4;
    const int li = lane & 15;

    const float* cnorm = ws + W_CNORM;
    const half8* cbp = (const half8*)(ws + W_CBP);
    unsigned int* counts = (unsigned int*)ws;
    float* loss_sum = ws + W_LOSS;
    unsigned int* flagcnt = (unsigned int*)ws + W_FLAGCNT;
    unsigned int* flaglist = (unsigned int*)ws + W_FLAGLIST;

    // --- stationary B: wave w's 4 code-tiles (codes w*64 + ct*16 + li) ---
    half8 B0[4], B1[4];
    float cn[4];
#pragma unroll
    for (int ct = 0; ct < 4; ++ct) {
        const int T = w * 4 + ct;
        B0[ct] = cbp[(size_t)(T * 2 + 0) * 64 + lane];
        B1[ct] = cbp[(size_t)(T * 2 + 1) * 64 + lane];
        cn[ct] = cnorm[T * 16 + li];
    }

    float loss_acc = 0.f;     // leaders accumulate per-row best dists
    float x2acc = 0.f;        // wave 0 accumulates sum(x^2)

    for (int it = 0; it < ITERS; ++it) {
        const int rowbase = (blockIdx.x * ITERS + it) * 16;

        // stage 16-row x-tile (coalesced 4KB) -> LDS
        if (tid < 256) {
            const int r = tid >> 4, c = tid & 15;
            float4 v = *reinterpret_cast<const float4*>(x + (size_t)(rowbase + r) * CODE_DIM + c * 4);
            *reinterpret_cast<float4*>(&sx[r][c * 4]) = v;
        }
        __syncthreads();   // B1: sx ready

        // A-frag from LDS: row=li, k = 32f + 8lg + i
        float4 v0 = *reinterpret_cast<const float4*>(&sx[li][8 * lg]);
        float4 v1 = *reinterpret_cast<const float4*>(&sx[li][8 * lg + 4]);
        float4 v2 = *reinterpret_cast<const float4*>(&sx[li][32 + 8 * lg]);
        float4 v3 = *reinterpret_cast<const float4*>(&sx[li][32 + 8 * lg + 4]);
        float e[8] = {v0.x, v0.y, v0.z, v0.w, v1.x, v1.y, v1.z, v1.w};
        float g[8] = {v2.x, v2.y, v2.z, v2.w, v3.x, v3.y, v3.z, v3.w};
        half8 a0, a1;
#pragma unroll
        for (int i = 0; i < 8; ++i) {
            a0[i] = (_Float16)e[i];
            a1[i] = (_Float16)g[i];
            if (w == 0) {               // each element appears exactly once in wave 0
                x2acc = fmaf(e[i], e[i], x2acc);
                x2acc = fmaf(g[i], g[i], x2acc);
            }
        }

        // distances for 16 rows x this wave's 64 codes; exact (b, j, s) tracking
        float b[4], s[4];
        int j[4];
#pragma unroll
        for (int r = 0; r < 4; ++r) { b[r] = FLT_MAX; s[r] = FLT_MAX; j[r] = 0x7fffffff; }

#pragma unroll
        for (int ct = 0; ct < 4; ++ct) {
            f32x4 ci = {cn[ct], cn[ct], cn[ct], cn[ct]};
            f32x4 acc = __builtin_amdgcn_mfma_f32_16x16x32_f16(a0, B0[ct], ci, 0, 0, 0);
            acc = __builtin_amdgcn_mfma_f32_16x16x32_f16(a1, B1[ct], acc, 0, 0, 0);
            const int code = w * 64 + ct * 16 + li;
#pragma unroll
            for (int r = 0; r < 4; ++r) {
                float d = acc[r];
                s[r] = fminf(s[r], fmaxf(b[r], d));
                bool take = d < b[r];               // ct ascending -> first occurrence
                b[r] = take ? d : b[r];
                j[r] = take ? code : j[r];
            }
        }

        // reduce across the 16 lanes of each group (rows 4*lg + r)
#pragma unroll
        for (int r = 0; r < 4; ++r) {
#pragma unroll
            for (int m = 1; m <= 8; m <<= 1) {
                float ob = __shfl_xor(b[r], m, 64);
                float os = __shfl_xor(s[r], m, 64);
                int   oj = __shfl_xor(j[r], m, 64);
                s[r] = fminf(fminf(s[r], os), fmaxf(b[r], ob));
                bool take = (ob < b[r]) || (ob == b[r] && oj < j[r]);
                if (take) { b[r] = ob; j[r] = oj; }
            }
        }
        if (li == 0) {
#pragma unroll
            for (int r = 0; r < 4; ++r) {
                spb[w][4 * lg + r] = __float_as_uint(b[r]);
                spj[w][4 * lg + r] = j[r];
                sps[w][4 * lg + r] = s[r];
            }
        }
        __syncthreads();   // B2: partials ready (and all sx reads done)

        // merge 16 wave-partials per row (threads 0..255; row = tid>>4)
        if (tid < 256) {
            const int row = tid >> 4, wp = tid & 15;
            float mb = __uint_as_float(spb[wp][row]);
            int   mj = spj[wp][row];
            float ms = sps[wp][row];
#pragma unroll
            for (int m = 1; m <= 8; m <<= 1) {
                float ob = __shfl_xor(mb, m, 64);
                float os = __shfl_xor(ms, m, 64);
                int   oj = __shfl_xor(mj, m, 64);
                ms = fminf(fminf(ms, os), fmaxf(mb, ob));
                bool take = (ob < mb) || (ob == mb && oj < mj);
                if (take) { mb = ob; mj = oj; }
            }
            if (wp == 0) {             // row leader
                sj[row] = mj;
                atomicAdd(&counts[mj], 1u);
                loss_acc += mb;        // loss_row = ||x||^2 + (||c||^2 - 2 x.c)
                if (ms - mb <= TAU) {
                    unsigned pos = atomicAdd(flagcnt, 1u);
                    if (pos < flag_cap)
                        flaglist[pos] = ((unsigned)(rowbase + row) << 10) | (unsigned)mj;
                }
            }
        }
        __syncthreads();   // B3: sj ready

        // dequant: 16 threads per row write the winning codebook row
        if (tid < 256) {
            const int row = tid >> 4, c = tid & 15;
            const int jj = sj[row];
            float4 v = *reinterpret_cast<const float4*>(cb + (size_t)jj * CODE_DIM + c * 4);
            *reinterpret_cast<float4*>(out + (size_t)(rowbase + row) * CODE_DIM + c * 4) = v;
        }
    }

    // epilogue: fold scalars into global accumulators
    if (w == 0) {
#pragma unroll
        for (int m = 32; m >= 1; m >>= 1) x2acc += __shfl_down(x2acc, m, 64);
        if (lane == 0) atomicAdd(loss_sum, x2acc);
    }
    if (tid < 256 && (tid & 15) == 0) atomicAdd(loss_sum, loss_acc);
}

// ---- exact f32 re-solve for flagged (near-tie) rows: one wave per row ----
__global__ __launch_bounds__(256) void fixup_kernel(
    const float* __restrict__ x, const float* __restrict__ cb,
    float* __restrict__ ws, float* __restrict__ out, unsigned int flag_cap)
{
    unsigned nf = *((unsigned*)ws + W_FLAGCNT);
    if (nf > flag_cap) nf = flag_cap;
    const float* cnorm = ws + W_CNORM;
    unsigned* flaglist = (unsigned*)ws + W_FLAGLIST;
    unsigned* counts = (unsigned*)ws;

    const int lane = threadIdx.x & 63;
    const unsigned wave_id = (blockIdx.x * blockDim.x + threadIdx.x) >> 6;
    const unsigned nwaves = (gridDim.x * blockDim.x) >> 6;

    for (unsigned idx = wave_id; idx < nf; idx += nwaves) {
        unsigned e = flaglist[idx];
        int row = (int)(e >> 10);
        int oldj = (int)(e & 1023u);

        float xr[CODE_DIM];
        const float4* x4 = reinterpret_cast<const float4*>(x + (size_t)row * CODE_DIM);
#pragma unroll
        for (int q = 0; q < 16; ++q) {
            float4 v = x4[q];
            xr[4 * q + 0] = v.x; xr[4 * q + 1] = v.y;
            xr[4 * q + 2] = v.z; xr[4 * q + 3] = v.w;
        }

        float bestv = FLT_MAX; int bj = 0x7fffffff;
        for (int t = 0; t < 16; ++t) {
            int j = lane * 16 + t;     // ascending within lane -> first occurrence kept
            const float* c = cb + (size_t)j * CODE_DIM;
            float d0 = 0.f, d1 = 0.f, d2 = 0.f, d3 = 0.f;
#pragma unroll
            for (int k = 0; k < CODE_DIM; k += 4) {
                d0 = fmaf(xr[k + 0], c[k + 0], d0);
                d1 = fmaf(xr[k + 1], c[k + 1], d1);
                d2 = fmaf(xr[k + 2], c[k + 2], d2);
                d3 = fmaf(xr[k + 3], c[k + 3], d3);
            }
            float dist = fmaf(-2.f, (d0 + d1) + (d2 + d3), cnorm[j]);
            if (dist < bestv) { bestv = dist; bj = j; }
        }
#pragma unroll
        for (int m = 1; m <= 32; m <<= 1) {
            float ob = __shfl_xor(bestv, m, 64);
            int   oj = __shfl_xor(bj, m, 64);
            bool take = (ob < bestv) || (ob == bestv && oj < bj);
            if (take) { bestv = ob; bj = oj; }
        }

        if (bj != oldj) {
            if (lane < 16) {
                *reinterpret_cast<float4*>(out + (size_t)row * CODE_DIM + lane * 4) =
                    *reinterpret_cast<const float4*>(cb + (size_t)bj * CODE_DIM + lane * 4);
            }
            if (lane == 0) {
                atomicAdd(&counts[bj], 1u);
                atomicAdd(&counts[oldj], (unsigned)-1);
            }
        }
    }
}

__global__ void finalize_kernel(const unsigned int* __restrict__ counts,
                                const float* __restrict__ loss_sum,
                                float* __restrict__ out)
{
    __shared__ float red[NB_CODE];
    int t = threadIdx.x;
    float p = (float)counts[t] / (float)NROWS;
    red[t] = p * logf(p + 1e-7f);
    __syncthreads();
    for (int s = NB_CODE / 2; s > 0; s >>= 1) {
        if (t < s) red[t] += red[t + s];
        __syncthreads();
    }
    if (t == 0) {
        out[NTC + 0] = *loss_sum / (float)NTC;
        out[NTC + 1] = expf(-red[0]);
    }
}

extern "C" void kernel_launch(void* const* d_in, const int* in_sizes, int n_in,
                              void* d_out, int out_size, void* d_ws, size_t ws_size,
                              hipStream_t stream) {
    const float* x  = (const float*)d_in[0];
    const float* cb = (const float*)d_in[1];
    float* out = (float*)d_out;
    float* ws = (float*)d_ws;

    unsigned flag_cap = 0;
    size_t words = ws_size / 4;
    if (words > (size_t)W_FLAGLIST) flag_cap = (unsigned)(words - W_FLAGLIST);
    if (flag_cap > NROWS) flag_cap = NROWS;

    // zero counts + loss + flagcnt each call (ws not re-poisoned between replays)
    hipMemsetAsync(d_ws, 0, 1028 * sizeof(float), stream);

    prep_kernel<<<NB_CODE / 256, 256, 0, stream>>>(cb, ws);
    vq_cs_kernel<<<NBLK, 1024, 0, stream>>>(x, cb, ws, out, flag_cap);
    fixup_kernel<<<2048, 256, 0, stream>>>(x, cb, ws, out, flag_cap);
    finalize_kernel<<<1, NB_CODE, 0, stream>>>((unsigned int*)ws, ws + W_LOSS, out);
}

// Round 13
// 277.644 us; speedup vs baseline: 1.7748x; 1.7748x over previous
//
#include <hip/hip_runtime.h>
#include <cfloat>
#include <cmath>

#define NB_CODE 1024
#define CODE_DIM 64
#define NROWS (32 * 8192)          // N*T = 262144
#define NTC ((size_t)NROWS * CODE_DIM)
#define TAU 0.04f                  // ~6 sigma of single-f16-product + packing dist error

typedef __attribute__((ext_vector_type(8))) _Float16 half8;
typedef __attribute__((ext_vector_type(4))) float f32x4;

// ws layout (32-bit words):
//   0..1023      counts (u32)
//   1024         loss_sum (f32 atomic)
//   1026..1027   pad
//   1028..2051   cnorm f32[1024]
//   2052..34819  cbp: fragment-major f16 of (-2*cb), 128 KB
//                entry e = ((T*2 + f)*64 + lane), 16B each (T = tile 0..63)
#define W_LOSS 1024
#define W_CNORM 1028
#define W_CBP 2052

__device__ inline float unmask6(float v) {
    return __uint_as_float(__float_as_uint(v) & 0xFFFFFFC0u);
}

// ---- prep: cnorm + fragment-major f16 of (-2*codebook) ----
// B-frag (16x16x32): lane = lg*16+li holds col=li, k = 32*f + 8*lg + i.
__global__ void prep_kernel(const float* __restrict__ cb, float* __restrict__ ws) {
    int j = blockIdx.x * blockDim.x + threadIdx.x;
    if (j >= NB_CODE) return;
    float* cnorm = ws + W_CNORM;
    half8* cbp = (half8*)(ws + W_CBP);
    const int t = j >> 4, li = j & 15;

    float c2v[CODE_DIM];
    const float4* c4 = reinterpret_cast<const float4*>(cb + (size_t)j * CODE_DIM);
    float s = 0.f;
#pragma unroll
    for (int q = 0; q < 16; ++q) {
        float4 v = c4[q];
        float e[4] = {v.x, v.y, v.z, v.w};
#pragma unroll
        for (int u = 0; u < 4; ++u) {
            s = fmaf(e[u], e[u], s);
            c2v[q * 4 + u] = -2.f * e[u];
        }
    }
    cnorm[j] = s;

#pragma unroll
    for (int f = 0; f < 2; ++f) {
#pragma unroll
        for (int lg = 0; lg < 4; ++lg) {
            half8 h8;
#pragma unroll
            for (int i = 0; i < 8; ++i)
                h8[i] = (_Float16)c2v[32 * f + 8 * lg + i];   // RNE
            cbp[(size_t)(t * 2 + f) * 64 + lg * 16 + li] = h8;
        }
    }
}

// ---- main: LDS-staged single-f16-product MFMA argmin + INLINE exact fixup ----
// 512 threads = 8 waves, 32 rows/wave -> 256 rows/block, 1024 blocks.
// LDS: 32KB sB + 4KB scn + 1KB lds_j + flags ~= 38KB -> 3-4 blocks/CU.
__global__ __launch_bounds__(512) void vq_kernel(
    const float* __restrict__ x, const float* __restrict__ cb,
    float* __restrict__ ws, float* __restrict__ out)
{
    __shared__ half8 sB[2048];        // 32 KB: 16 tiles x 2 chunks x 64 lanes
    __shared__ float scn[NB_CODE];    // 4 KB
    __shared__ int lds_j[256];        // 1 KB
    __shared__ unsigned sflag[8];     // per-wave flagged-row bitmask

    const int tid = threadIdx.x;
    const int w = tid >> 6, lane = tid & 63;
    const int lg = lane >> 4;
    const int li = lane & 15;
    const int wavebase = blockIdx.x * 256 + w * 32;

    const float* cnorm_g = ws + W_CNORM;
    const half8* cbp = (const half8*)(ws + W_CBP);
    unsigned int* counts = (unsigned int*)ws;
    float* loss_sum = ws + W_LOSS;

    // stage one 32KB phase (16 tiles) via async global->LDS, width 16
#define STAGE(phx)                                                              \
    {                                                                           \
        const half8* gsrc_ = cbp + (size_t)(phx) * 2048;                        \
        _Pragma("unroll")                                                       \
        for (int k_ = 0; k_ < 4; ++k_) {                                        \
            const int o_ = k_ * 512 + w * 64;                                   \
            __builtin_amdgcn_global_load_lds(                                   \
                (const __attribute__((address_space(1))) unsigned int*)(gsrc_ + o_ + lane), \
                (__attribute__((address_space(3))) unsigned int*)&sB[o_],       \
                16, 0, 0);                                                      \
        }                                                                       \
    }

    STAGE(0);

    // --- x prologue (overlaps staging): f16 A-frags + sum(x^2) ---
    half8 xh[2][2];
    float x2sum = 0.f;
#pragma unroll
    for (int rt = 0; rt < 2; ++rt) {
        const float* xr = x + (size_t)(wavebase + rt * 16 + li) * CODE_DIM;
#pragma unroll
        for (int f = 0; f < 2; ++f) {
            const float4* p = reinterpret_cast<const float4*>(xr + 32 * f + 8 * lg);
            float4 v0 = p[0], v1 = p[1];
            float e[8] = {v0.x, v0.y, v0.z, v0.w, v1.x, v1.y, v1.z, v1.w};
            half8 h8;
#pragma unroll
            for (int i = 0; i < 8; ++i) {
                float xe = e[i];
                x2sum = fmaf(xe, xe, x2sum);
                h8[i] = (_Float16)xe;                // RNE, err ~2^-11 rel
            }
            xh[rt][f] = h8;
        }
    }
    for (int i = tid; i < NB_CODE; i += 512) scn[i] = cnorm_g[i];
    if (tid < 8) sflag[tid] = 0u;

    asm volatile("s_waitcnt vmcnt(0)" ::: "memory");
    __builtin_amdgcn_sched_barrier(0);
    __syncthreads();                                 // sB[ph0] + scn ready

    float best[2][4], second[2][4];
#pragma unroll
    for (int rt = 0; rt < 2; ++rt)
#pragma unroll
        for (int r = 0; r < 4; ++r) { best[rt][r] = FLT_MAX; second[rt][r] = FLT_MAX; }

    // --- 4 phases x 16 tiles ---
    for (int ph = 0; ph < 4; ++ph) {
        for (int tl = 0; tl < 16; ++tl) {
            const int T = ph * 16 + tl;
            half8 b0 = sB[tl * 128 + lane];
            half8 b1 = sB[tl * 128 + 64 + lane];
            float cn = scn[T * 16 + li];
            f32x4 ci = {cn, cn, cn, cn};
#pragma unroll
            for (int rt = 0; rt < 2; ++rt) {
                f32x4 acc = __builtin_amdgcn_mfma_f32_16x16x32_f16(xh[rt][0], b0, ci, 0, 0, 0);
                acc = __builtin_amdgcn_mfma_f32_16x16x32_f16(xh[rt][1], b1, acc, 0, 0, 0);
#pragma unroll
                for (int r = 0; r < 4; ++r) {
                    // pack tile id into mantissa LSBs (near-ties flagged + re-solved)
                    float p = __uint_as_float((__float_as_uint(acc[r]) & 0xFFFFFFC0u) | (unsigned)T);
                    second[rt][r] = fminf(second[rt][r], fmaxf(best[rt][r], p));
                    best[rt][r] = fminf(best[rt][r], p);
                }
            }
        }
        if (ph < 3) {
            __syncthreads();                          // all waves done with sB
            STAGE(ph + 1);
            asm volatile("s_waitcnt vmcnt(0)" ::: "memory");
            __builtin_amdgcn_sched_barrier(0);
            __syncthreads();                          // next phase visible
        }
    }
#undef STAGE

    // --- per-row reduce across the 16 lanes of each group ---
#pragma unroll
    for (int rt = 0; rt < 2; ++rt)
#pragma unroll
        for (int r = 0; r < 4; ++r) {
            float b = best[rt][r], s = second[rt][r];
            int code = ((int)(__float_as_uint(b) & 63u) << 4) | li;
#pragma unroll
            for (int m = 1; m <= 8; m <<= 1) {
                float ob = __shfl_xor(b, m, 64);
                float os = __shfl_xor(s, m, 64);
                int   oc = __shfl_xor(code, m, 64);
                s = fminf(fminf(s, os), fmaxf(b, ob));
                bool take = (ob < b) || (ob == b && oc < code);
                if (take) { b = ob; code = oc; }
            }
            best[rt][r] = b; second[rt][r] = s;
            // stash per-row results via leaders below
            if (li == 0) {
                int rowin = rt * 16 + lg * 4 + r;
                lds_j[w * 32 + rowin] = code;
            }
        }

    // --- stats + flag collection (leaders: lanes 0,16,32,48) ---
    float lsum = x2sum;
    if (li == 0) {
        unsigned bits = 0;
#pragma unroll
        for (int rt = 0; rt < 2; ++rt)
#pragma unroll
            for (int r = 0; r < 4; ++r) {
                int rowin = rt * 16 + lg * 4 + r;
                int j = lds_j[w * 32 + rowin];
                atomicAdd(&counts[j], 1u);
                float bd = unmask6(best[rt][r]);
                lsum += bd;                    // loss_row = ||x||^2 + (||c||^2 - 2 x.c)
                if (unmask6(second[rt][r]) - bd <= TAU) bits |= 1u << rowin;
            }
        if (bits) atomicOr(&sflag[w], bits);
    }
#pragma unroll
    for (int m = 32; m >= 1; m >>= 1) lsum += __shfl_down(lsum, m, 64);
    if (lane == 0) atomicAdd(loss_sum, lsum);

    __syncthreads();                                 // sflag/lds_j visible

    // --- INLINE exact f32 re-solve for this wave's flagged rows ---
    unsigned fm = sflag[w];
    while (fm) {
        const int row = __ffs(fm) - 1;
        fm &= fm - 1;
        const int rowg = wavebase + row;

        // whole wave loads the same x row (broadcast, L2-hot)
        float xr[CODE_DIM];
        const float4* x4 = reinterpret_cast<const float4*>(x + (size_t)rowg * CODE_DIM);
#pragma unroll
        for (int q = 0; q < 16; ++q) {
            float4 v = x4[q];
            xr[4 * q + 0] = v.x; xr[4 * q + 1] = v.y;
            xr[4 * q + 2] = v.z; xr[4 * q + 3] = v.w;
        }
        float bestv = FLT_MAX; int bj = 0x7fffffff;
        for (int t = 0; t < 16; ++t) {
            int j = lane * 16 + t;     // ascending within lane -> first occurrence kept
            const float* c = cb + (size_t)j * CODE_DIM;
            float d0 = 0.f, d1 = 0.f, d2 = 0.f, d3 = 0.f;
#pragma unroll
            for (int k = 0; k < CODE_DIM; k += 4) {
                d0 = fmaf(xr[k + 0], c[k + 0], d0);
                d1 = fmaf(xr[k + 1], c[k + 1], d1);
                d2 = fmaf(xr[k + 2], c[k + 2], d2);
                d3 = fmaf(xr[k + 3], c[k + 3], d3);
            }
            float dist = fmaf(-2.f, (d0 + d1) + (d2 + d3), scn[j]);
            if (dist < bestv) { bestv = dist; bj = j; }
        }
#pragma unroll
        for (int m = 1; m <= 32; m <<= 1) {
            float ob = __shfl_xor(bestv, m, 64);
            int   oj = __shfl_xor(bj, m, 64);
            bool take = (ob < bestv) || (ob == bestv && oj < bj);
            if (take) { bestv = ob; bj = oj; }
        }
        if (lane == 0) {
            int old = lds_j[w * 32 + row];
            if (bj != old) {
                lds_j[w * 32 + row] = bj;
                atomicAdd(&counts[bj], 1u);
                atomicAdd(&counts[old], (unsigned)-1);
            }
        }
    }

    // --- dequant write (after fixes): 4 rows/iter, float4 per lane ---
    for (int it = 0; it < 8; ++it) {
        int rowin = it * 4 + lg;
        int j = lds_j[w * 32 + rowin];
        float4 v = *reinterpret_cast<const float4*>(cb + (size_t)j * CODE_DIM + li * 4);
        *reinterpret_cast<float4*>(out + (size_t)(wavebase + rowin) * CODE_DIM + li * 4) = v;
    }
}

__global__ void finalize_kernel(const unsigned int* __restrict__ counts,
                                const float* __restrict__ loss_sum,
                                float* __restrict__ out)
{
    __shared__ float red[NB_CODE];
    int t = threadIdx.x;
    float p = (float)counts[t] / (float)NROWS;
    red[t] = p * logf(p + 1e-7f);
    __syncthreads();
    for (int s = NB_CODE / 2; s > 0; s >>= 1) {
        if (t < s) red[t] += red[t + s];
        __syncthreads();
    }
    if (t == 0) {
        out[NTC + 0] = *loss_sum / (float)NTC;
        out[NTC + 1] = expf(-red[0]);
    }
}

extern "C" void kernel_launch(void* const* d_in, const int* in_sizes, int n_in,
                              void* d_out, int out_size, void* d_ws, size_t ws_size,
                              hipStream_t stream) {
    const float* x  = (const float*)d_in[0];
    const float* cb = (const float*)d_in[1];
    float* out = (float*)d_out;
    float* ws = (float*)d_ws;

    // zero counts + loss each call (ws not re-poisoned between replays)
    hipMemsetAsync(d_ws, 0, 1028 * sizeof(float), stream);

    prep_kernel<<<NB_CODE / 256, 256, 0, stream>>>(cb, ws);
    vq_kernel<<<NROWS / 256, 512, 0, stream>>>(x, cb, ws, out);
    finalize_kernel<<<1, NB_CODE, 0, stream>>>((unsigned int*)ws, ws + W_LOSS, out);
}